// Round 8
// baseline (155.567 us; speedup 1.0000x reference)
//
#include <hip/hip_runtime.h>

#define LL 2048
#define DD 64
#define BB 8
#define EPSF 1e-8f

typedef short bf16x8 __attribute__((ext_vector_type(8)));
typedef float f32x4 __attribute__((ext_vector_type(4)));
typedef float f32x8 __attribute__((ext_vector_type(8)));

__device__ __forceinline__ ushort f2bf(float f) {  // RNE float->bf16
    uint u = __float_as_uint(f);
    return (ushort)((u + 0x7fffu + ((u >> 16) & 1u)) >> 16);
}
__device__ __forceinline__ float bf2f(ushort h) {
    return __uint_as_float((uint)h << 16);
}

// Prepass: normalize y rows (fp32 math), store bf16 HI only. 32 rows/block.
__global__ __launch_bounds__(256) void norm_y_kernel(
    const float* __restrict__ y, ushort* __restrict__ yh) {
    const int row = blockIdx.x * 32 + (threadIdx.x >> 3);  // 0..16383
    const int oct = threadIdx.x & 7;
    const float* g = y + (size_t)row * DD;
    float4 v0 = *reinterpret_cast<const float4*>(g + oct * 4);
    float4 v1 = *reinterpret_cast<const float4*>(g + 32 + oct * 4);
    float ss = v0.x*v0.x + v0.y*v0.y + v0.z*v0.z + v0.w*v0.w
             + v1.x*v1.x + v1.y*v1.y + v1.z*v1.z + v1.w*v1.w;
    ss += __shfl_xor(ss, 1);
    ss += __shfl_xor(ss, 2);
    ss += __shfl_xor(ss, 4);
    const float sc = 1.0f / fmaxf(sqrtf(ss), EPSF);
    const size_t base = (size_t)row * DD + oct * 4;
    *reinterpret_cast<ushort4*>(yh + base) =
        make_ushort4(f2bf(v0.x*sc), f2bf(v0.y*sc), f2bf(v0.z*sc), f2bf(v0.w*sc));
    *reinterpret_cast<ushort4*>(yh + base + 32) =
        make_ushort4(f2bf(v1.x*sc), f2bf(v1.y*sc), f2bf(v1.z*sc), f2bf(v1.w*sc));
}

// One block = (batch b, 32-q-row strip); 2-D grid (x=strip, y=batch). 512 threads =
// 8 waves; wave w owns a 64-col slice of each 512-col step (4 steps cover 2048).
// 16 waves/CU at 2 blocks/CU -> store-drain + load-wait hidden by cross-wave TLP
// (R3/R6 evidence: intra-wave prefetch neutral at 8 waves/CU, so TLP is the lever).
// q normalized + hi/lo split in-kernel (strip-private, 2 shuffles). y = bf16 hi only:
// acc = yh*(qh+ql), dot error ~2^-12. MFMA operands swapped (A=y M-side, B=q N-side):
// D col=lane&15 = q row, row=kg*4+j = y col -> f32x4 stores along output cols and a
// per-lane running row-max.
__global__ __launch_bounds__(512, 4) void att_mfma_kernel(
    const float* __restrict__ q, const ushort* __restrict__ yhg,
    float* __restrict__ out) {
    const int b       = blockIdx.y;
    const int rowBase = blockIdx.x * 32;
    const int t  = threadIdx.x;
    const int w  = t >> 6;   // 0..7
    const int l  = t & 63;
    const int ln = l & 15;   // q row within 16-subtile
    const int kg = l >> 4;   // k-group; in D: y-col group of 4

    // ---- inline q normalize + hi/lo split into fragments ----
    bf16x8 qhf[2][2], qlf[2][2];
    #pragma unroll
    for (int mq = 0; mq < 2; ++mq) {
        f32x8 v[2];
        #pragma unroll
        for (int kk = 0; kk < 2; ++kk)
            v[kk] = *reinterpret_cast<const f32x8*>(
                q + ((size_t)(b * LL + rowBase + mq * 16 + ln)) * DD + kk * 32 + kg * 8);
        float ss = 0.f;
        #pragma unroll
        for (int kk = 0; kk < 2; ++kk)
            #pragma unroll
            for (int j = 0; j < 8; ++j) ss += v[kk][j] * v[kk][j];
        ss += __shfl_xor(ss, 16);   // combine the 4 kg chunks of this row
        ss += __shfl_xor(ss, 32);
        const float sc = 1.0f / fmaxf(sqrtf(ss), EPSF);
        #pragma unroll
        for (int kk = 0; kk < 2; ++kk)
            #pragma unroll
            for (int j = 0; j < 8; ++j) {
                const float f = v[kk][j] * sc;
                const ushort h = f2bf(f);
                qhf[mq][kk][j] = (short)h;
                qlf[mq][kk][j] = (short)f2bf(f - bf2f(h));
            }
    }

    float rmax[2] = {-1e30f, -1e30f};  // per-lane: q row = rowBase + mq*16 + ln

    for (int ct = 0; ct < 4; ++ct) {
        const int colBase = ct * 512 + w * 64;

        bf16x8 yh[4][2];
        #pragma unroll
        for (int ny = 0; ny < 4; ++ny)
            #pragma unroll
            for (int kk = 0; kk < 2; ++kk)
                yh[ny][kk] = *reinterpret_cast<const bf16x8*>(
                    yhg + ((size_t)(b * LL + colBase + ny * 16 + ln)) * DD
                        + kk * 32 + kg * 8);

        f32x4 acc[2][4];
        #pragma unroll
        for (int mq = 0; mq < 2; ++mq)
            #pragma unroll
            for (int ny = 0; ny < 4; ++ny)
                acc[mq][ny] = (f32x4){0.f, 0.f, 0.f, 0.f};

        #pragma unroll
        for (int kk = 0; kk < 2; ++kk)
            #pragma unroll
            for (int mq = 0; mq < 2; ++mq)
                #pragma unroll
                for (int ny = 0; ny < 4; ++ny)
                    acc[mq][ny] = __builtin_amdgcn_mfma_f32_16x16x32_bf16(
                        yh[ny][kk], qlf[mq][kk], acc[mq][ny], 0, 0, 0);
        #pragma unroll
        for (int kk = 0; kk < 2; ++kk)
            #pragma unroll
            for (int mq = 0; mq < 2; ++mq)
                #pragma unroll
                for (int ny = 0; ny < 4; ++ny)
                    acc[mq][ny] = __builtin_amdgcn_mfma_f32_16x16x32_bf16(
                        yh[ny][kk], qhf[mq][kk], acc[mq][ny], 0, 0, 0);

        #pragma unroll
        for (int mq = 0; mq < 2; ++mq)
            #pragma unroll
            for (int ny = 0; ny < 4; ++ny) {
                f32x4 v = acc[mq][ny];
                *reinterpret_cast<f32x4*>(
                    out + ((size_t)(b * LL + rowBase + mq * 16 + ln)) * LL
                        + colBase + ny * 16 + kg * 4) = v;
                rmax[mq] = fmaxf(rmax[mq],
                           fmaxf(fmaxf(v[0], v[1]), fmaxf(v[2], v[3])));
            }
    }

    // rmax[mq] covers this lane's q-row over this wave's cols. Combine kg groups
    // (lane bits 4,5), then the 8 waves via LDS.
    #pragma unroll
    for (int mq = 0; mq < 2; ++mq) {
        rmax[mq] = fmaxf(rmax[mq], __shfl_xor(rmax[mq], 16));
        rmax[mq] = fmaxf(rmax[mq], __shfl_xor(rmax[mq], 32));
    }

    __shared__ float smax[8][32];
    if (kg == 0) {
        smax[w][ln]      = rmax[0];
        smax[w][16 + ln] = rmax[1];
    }
    __syncthreads();
    if (t < 32) {
        float v = smax[0][t];
        #pragma unroll
        for (int ww = 1; ww < 8; ++ww) v = fmaxf(v, smax[ww][t]);
        out[(size_t)BB * LL * LL + (size_t)b * LL + rowBase + t] = v;
    }
}

extern "C" void kernel_launch(void* const* d_in, const int* in_sizes, int n_in,
                              void* d_out, int out_size, void* d_ws, size_t ws_size,
                              hipStream_t stream) {
    const float* q = (const float*)d_in[0];
    const float* y = (const float*)d_in[1];
    float* out     = (float*)d_out;
    ushort* yh     = (ushort*)d_ws;  // needs 4 MB

    norm_y_kernel<<<dim3(512), dim3(256), 0, stream>>>(y, yh);
    att_mfma_kernel<<<dim3(LL / 32, BB), dim3(512), 0, stream>>>(q, yh, out);
}